// Round 1
// baseline (1085.424 us; speedup 1.0000x reference)
//
#include <hip/hip_runtime.h>
#include <hip/hip_bf16.h>

// Problem constants (B, D, DOUT from reference)
#define BDIM 8192
#define DDIM 4096
#define DOUTD 4096

typedef __attribute__((ext_vector_type(8))) short short8;
typedef __attribute__((ext_vector_type(4))) float floatx4;

// round-to-nearest-even fp32 -> bf16 (bit pattern)
__device__ inline unsigned short f32_to_bf16_rne(float f) {
    unsigned int u = __float_as_uint(f);
    unsigned int lsb = (u >> 16) & 1u;
    u += 0x7fffu + lsb;
    return (unsigned short)(u >> 16);
}

// async global->LDS, 16B per lane; lds base must be wave-uniform
__device__ inline void gload_lds16(const void* g, void* lds) {
    __builtin_amdgcn_global_load_lds(
        (const __attribute__((address_space(1))) void*)g,
        (__attribute__((address_space(3))) void*)lds,
        16, 0, 0);
}

// Convert x (fp32 [B,D]) to bf16 natural (xb [B,D]) and transposed (xT [D,B]).
__global__ __launch_bounds__(256)
void convert_transpose_x(const float* __restrict__ x,
                         unsigned short* __restrict__ xb,
                         unsigned short* __restrict__ xT) {
    __shared__ __align__(16) unsigned short tile[64][72];  // [d][b], +8 pad
    const int t = threadIdx.x;
    const int tb = blockIdx.x * 64;   // b offset
    const int td = blockIdx.y * 64;   // d offset
#pragma unroll
    for (int p = 0; p < 4; ++p) {
        int c = t + p * 256;            // [0,1024)
        int row  = c >> 4;              // b-local
        int col4 = (c & 15) << 2;       // d-local
        float4 v = *(const float4*)&x[(size_t)(tb + row) * DDIM + td + col4];
        ushort4 o;
        o.x = f32_to_bf16_rne(v.x);
        o.y = f32_to_bf16_rne(v.y);
        o.z = f32_to_bf16_rne(v.z);
        o.w = f32_to_bf16_rne(v.w);
        *(ushort4*)&xb[(size_t)(tb + row) * DDIM + td + col4] = o;
        tile[col4 + 0][row] = o.x;
        tile[col4 + 1][row] = o.y;
        tile[col4 + 2][row] = o.z;
        tile[col4 + 3][row] = o.w;
    }
    __syncthreads();
#pragma unroll
    for (int p = 0; p < 4; ++p) {
        int c = t + p * 256;
        int drow = c >> 4;              // d-local
        int b4   = (c & 15) << 2;       // b-local
        ushort4 o = *(const ushort4*)&tile[drow][b4];
        *(ushort4*)&xT[(size_t)(td + drow) * BDIM + tb + b4] = o;
    }
}

// Elementwise fp32 -> bf16 for W
__global__ __launch_bounds__(256)
void convert_w_kernel(const float* __restrict__ W, unsigned short* __restrict__ Wb) {
    size_t i = ((size_t)blockIdx.x * 256 + threadIdx.x) * 4;
    float4 v = *(const float4*)&W[i];
    ushort4 o;
    o.x = f32_to_bf16_rne(v.x);
    o.y = f32_to_bf16_rne(v.y);
    o.z = f32_to_bf16_rne(v.z);
    o.w = f32_to_bf16_rne(v.w);
    *(ushort4*)&Wb[i] = o;
}

// C[m,n] = sum_k A[m,k]*B[n,k]  (+ bias[n]  or  + eps on diagonal)
// A: [M,K] bf16 row-major, B: [N,K] bf16 row-major, C: [M,N] fp32.
// 128x128 block tile, BK=32, 256 threads = 4 waves (2x2), wave tile 64x64.
template <bool HESS>
__global__ __launch_bounds__(256)
void gemm_nt(const unsigned short* __restrict__ A,
             const unsigned short* __restrict__ B,
             const float* __restrict__ bias,
             float* __restrict__ C,
             int M, int N, int K) {
    constexpr int BK = 32;
    __shared__ __align__(16) unsigned short As[128 * BK];  // [m][k]
    __shared__ __align__(16) unsigned short Bs[128 * BK];  // [n][k]

    const int t    = threadIdx.x;
    const int lane = t & 63;
    const int wave = t >> 6;
    const int quad = lane >> 4;
    const int r    = lane & 15;
    const size_t bm = (size_t)blockIdx.x * 128;
    const size_t bn = (size_t)blockIdx.y * 128;
    const int wm = (wave & 1) * 64;
    const int wn = (wave >> 1) * 64;

    // staging: chunk c = t (call 0) and t+256 (call 1); each chunk = 16B = 8 bf16
    const int arow0 = t >> 2;           // 0..63
    const int akc0  = (t & 3) * 8;      // k offset within BK
    const unsigned short* gA0 = A + (bm + arow0) * (size_t)K + akc0;
    const unsigned short* gA1 = gA0 + (size_t)64 * K;
    const unsigned short* gB0 = B + (bn + arow0) * (size_t)K + akc0;
    const unsigned short* gB1 = gB0 + (size_t)64 * K;
    char* ldsA0 = (char*)As + wave * 1024;
    char* ldsA1 = ldsA0 + 4096;
    char* ldsB0 = (char*)Bs + wave * 1024;
    char* ldsB1 = ldsB0 + 4096;

    floatx4 acc[4][4];
#pragma unroll
    for (int i = 0; i < 4; ++i)
#pragma unroll
        for (int j = 0; j < 4; ++j)
            acc[i][j] = {0.f, 0.f, 0.f, 0.f};

    const int aoff = (wm + r) * BK + quad * 8;
    const int boff = (wn + r) * BK + quad * 8;

    for (int k0 = 0; k0 < K; k0 += BK) {
        gload_lds16(gA0 + k0, ldsA0);
        gload_lds16(gA1 + k0, ldsA1);
        gload_lds16(gB0 + k0, ldsB0);
        gload_lds16(gB1 + k0, ldsB1);
        __syncthreads();

        short8 af[4], bfr[4];
#pragma unroll
        for (int i = 0; i < 4; ++i) {
            af[i]  = *(const short8*)&As[aoff + i * 16 * BK];
            bfr[i] = *(const short8*)&Bs[boff + i * 16 * BK];
        }
#pragma unroll
        for (int i = 0; i < 4; ++i)
#pragma unroll
            for (int j = 0; j < 4; ++j)
                acc[i][j] = __builtin_amdgcn_mfma_f32_16x16x32_bf16(
                    af[i], bfr[j], acc[i][j], 0, 0, 0);
        __syncthreads();
    }

    // Epilogue: D layout col = lane&15 (n), row = quad*4 + reg (m)
    float bv[4];
#pragma unroll
    for (int j = 0; j < 4; ++j)
        bv[j] = HESS ? 0.f : bias[bn + wn + j * 16 + r];
#pragma unroll
    for (int i = 0; i < 4; ++i) {
        const size_t mb = bm + wm + i * 16 + quad * 4;
#pragma unroll
        for (int j = 0; j < 4; ++j) {
            const size_t n = bn + wn + j * 16 + r;
#pragma unroll
            for (int g = 0; g < 4; ++g) {
                float v = acc[i][j][g] + bv[j];
                if (HESS && (mb + g) == n) v += 1e-4f;
                C[(mb + g) * N + n] = v;
            }
        }
    }
}

extern "C" void kernel_launch(void* const* d_in, const int* in_sizes, int n_in,
                              void* d_out, int out_size, void* d_ws, size_t ws_size,
                              hipStream_t stream) {
    const float* x = (const float*)d_in[0];   // [8192, 4096]
    const float* W = (const float*)d_in[1];   // [4096, 4096]
    const float* b = (const float*)d_in[2];   // [4096]

    float* out  = (float*)d_out;                       // [8192, 4096]
    float* hess = out + (size_t)BDIM * DOUTD;          // [4096, 4096]

    // workspace layout (bf16): xb [B,D] | xT [D,B] | Wb [DOUT,D]  = 168 MB
    unsigned short* xb = (unsigned short*)d_ws;
    unsigned short* xT = xb + (size_t)BDIM * DDIM;
    unsigned short* Wb = xT + (size_t)BDIM * DDIM;

    convert_transpose_x<<<dim3(BDIM / 64, DDIM / 64), 256, 0, stream>>>(x, xb, xT);
    convert_w_kernel<<<((size_t)DOUTD * DDIM) / 1024, 256, 0, stream>>>(W, Wb);

    // out = x @ W.T + b : M=8192, N=4096, K=4096
    gemm_nt<false><<<dim3(BDIM / 128, DOUTD / 128), 256, 0, stream>>>(
        xb, Wb, b, out, BDIM, DOUTD, DDIM);
    // hess = xT @ xT.T + eps*I : M=N=4096, K=8192
    gemm_nt<true><<<dim3(DDIM / 128, DDIM / 128), 256, 0, stream>>>(
        xT, xT, nullptr, hess, DDIM, DDIM, BDIM);
}

// Round 2
// 1005.420 us; speedup vs baseline: 1.0796x; 1.0796x over previous
//
#include <hip/hip_runtime.h>
#include <hip/hip_bf16.h>

// Problem constants (B, D, DOUT from reference)
#define BDIM 8192
#define DDIM 4096
#define DOUTD 4096

typedef __attribute__((ext_vector_type(8))) short short8;
typedef __attribute__((ext_vector_type(16))) float floatx16;

// round-to-nearest-even fp32 -> bf16 (bit pattern)
__device__ inline unsigned short f32_to_bf16_rne(float f) {
    unsigned int u = __float_as_uint(f);
    unsigned int lsb = (u >> 16) & 1u;
    u += 0x7fffu + lsb;
    return (unsigned short)(u >> 16);
}

// async global->LDS, 16B per lane; lds base must be wave-uniform
__device__ inline void gload_lds16(const void* g, void* lds) {
    __builtin_amdgcn_global_load_lds(
        (const __attribute__((address_space(1))) void*)g,
        (__attribute__((address_space(3))) void*)lds,
        16, 0, 0);
}

// Convert x (fp32 [B,D]) to bf16 natural (xb [B,D]) and transposed (xT [D,B]).
__global__ __launch_bounds__(256)
void convert_transpose_x(const float* __restrict__ x,
                         unsigned short* __restrict__ xb,
                         unsigned short* __restrict__ xT) {
    __shared__ __align__(16) unsigned short tile[64][72];  // [d][b], +8 pad
    const int t = threadIdx.x;
    const int tb = blockIdx.x * 64;   // b offset
    const int td = blockIdx.y * 64;   // d offset
#pragma unroll
    for (int p = 0; p < 4; ++p) {
        int c = t + p * 256;            // [0,1024)
        int row  = c >> 4;              // b-local
        int col4 = (c & 15) << 2;       // d-local
        float4 v = *(const float4*)&x[(size_t)(tb + row) * DDIM + td + col4];
        ushort4 o;
        o.x = f32_to_bf16_rne(v.x);
        o.y = f32_to_bf16_rne(v.y);
        o.z = f32_to_bf16_rne(v.z);
        o.w = f32_to_bf16_rne(v.w);
        *(ushort4*)&xb[(size_t)(tb + row) * DDIM + td + col4] = o;
        tile[col4 + 0][row] = o.x;
        tile[col4 + 1][row] = o.y;
        tile[col4 + 2][row] = o.z;
        tile[col4 + 3][row] = o.w;
    }
    __syncthreads();
#pragma unroll
    for (int p = 0; p < 4; ++p) {
        int c = t + p * 256;
        int drow = c >> 4;              // d-local
        int b4   = (c & 15) << 2;       // b-local
        ushort4 o = *(const ushort4*)&tile[drow][b4];
        *(ushort4*)&xT[(size_t)(td + drow) * BDIM + tb + b4] = o;
    }
}

// Elementwise fp32 -> bf16 for W
__global__ __launch_bounds__(256)
void convert_w_kernel(const float* __restrict__ W, unsigned short* __restrict__ Wb) {
    size_t i = ((size_t)blockIdx.x * 256 + threadIdx.x) * 4;
    float4 v = *(const float4*)&W[i];
    ushort4 o;
    o.x = f32_to_bf16_rne(v.x);
    o.y = f32_to_bf16_rne(v.y);
    o.z = f32_to_bf16_rne(v.z);
    o.w = f32_to_bf16_rne(v.w);
    *(ushort4*)&Wb[i] = o;
}

// C[m,n] = sum_k A[m,k]*B[n,k]  (+ bias[n]  or  + eps on diagonal)
// A: [M,K] bf16 row-major, B: [N,K] bf16 row-major, C: [M,N] fp32.
// 128x128 block tile, BK=32, 256 threads = 4 waves (2x2), wave tile 64x64.
// MFMA: 32x32x16 bf16, 2x2 per wave.
// LDS XOR swizzle: 16B chunk kc of row r stored at position kc ^ ((r>>2)&3)
// -> conflict-free ds_read_b128 (exactly 2 lanes per 16B window per phase).
template <bool HESS>
__global__ __launch_bounds__(256)
void gemm_nt(const unsigned short* __restrict__ A,
             const unsigned short* __restrict__ B,
             const float* __restrict__ bias,
             float* __restrict__ C,
             int M, int N, int K) {
    constexpr int BK = 32;
    __shared__ __align__(16) unsigned short As[128 * BK];  // [m][k-chunk swizzled]
    __shared__ __align__(16) unsigned short Bs[128 * BK];  // [n][k-chunk swizzled]

    const int t    = threadIdx.x;
    const int lane = t & 63;
    const int wave = t >> 6;
    const int hi   = lane >> 5;        // 0/1 : k-half within MFMA operand
    const int lm   = lane & 31;        // m/n within 32-tile
    const int h    = (lane >> 2) & 3;  // swizzle key for rows this lane reads
    const size_t bm = (size_t)blockIdx.x * 128;
    const size_t bn = (size_t)blockIdx.y * 128;
    const int wm = (wave & 1) * 64;
    const int wn = (wave >> 1) * 64;

    // staging: row = t>>2 (0..63) and +64; fetch global chunk (t&3)^h(row)
    // where h(row) = ((t>>2)>>2)&3 = (t>>4)&3, so it lands at LDS position t&3.
    const int srow = t >> 2;
    const int kcg  = ((t & 3) ^ ((t >> 4) & 3)) * 8;  // shorts
    const unsigned short* gA0 = A + (bm + srow) * (size_t)K + kcg;
    const unsigned short* gA1 = gA0 + (size_t)64 * K;
    const unsigned short* gB0 = B + (bn + srow) * (size_t)K + kcg;
    const unsigned short* gB1 = gB0 + (size_t)64 * K;
    char* ldsA0 = (char*)As + wave * 1024;
    char* ldsA1 = ldsA0 + 4096;
    char* ldsB0 = (char*)Bs + wave * 1024;
    char* ldsB1 = ldsB0 + 4096;

    floatx16 acc[2][2];
#pragma unroll
    for (int i = 0; i < 2; ++i)
#pragma unroll
        for (int j = 0; j < 2; ++j)
#pragma unroll
            for (int g = 0; g < 16; ++g)
                acc[i][j][g] = 0.f;

    // read offsets (in shorts): row*BK + pos*8, pos = (2*s + hi) ^ h
    int aoff[2][2], boff[2][2];
#pragma unroll
    for (int i = 0; i < 2; ++i)
#pragma unroll
        for (int s = 0; s < 2; ++s) {
            int pos = ((2 * s + hi) ^ h) * 8;
            aoff[i][s] = (wm + 32 * i + lm) * BK + pos;
            boff[i][s] = (wn + 32 * i + lm) * BK + pos;
        }

    for (int k0 = 0; k0 < K; k0 += BK) {
        gload_lds16(gA0 + k0, ldsA0);
        gload_lds16(gA1 + k0, ldsA1);
        gload_lds16(gB0 + k0, ldsB0);
        gload_lds16(gB1 + k0, ldsB1);
        __syncthreads();

        short8 af[2][2], bf[2][2];
#pragma unroll
        for (int s = 0; s < 2; ++s)
#pragma unroll
            for (int i = 0; i < 2; ++i) {
                af[i][s] = *(const short8*)&As[aoff[i][s]];
                bf[i][s] = *(const short8*)&Bs[boff[i][s]];
            }
#pragma unroll
        for (int s = 0; s < 2; ++s) {
            acc[0][0] = __builtin_amdgcn_mfma_f32_32x32x16_bf16(af[0][s], bf[0][s], acc[0][0], 0, 0, 0);
            acc[0][1] = __builtin_amdgcn_mfma_f32_32x32x16_bf16(af[0][s], bf[1][s], acc[0][1], 0, 0, 0);
            acc[1][0] = __builtin_amdgcn_mfma_f32_32x32x16_bf16(af[1][s], bf[0][s], acc[1][0], 0, 0, 0);
            acc[1][1] = __builtin_amdgcn_mfma_f32_32x32x16_bf16(af[1][s], bf[1][s], acc[1][1], 0, 0, 0);
        }
        __syncthreads();
    }

    // Epilogue: D layout col = lane&31 (n), row = (reg&3) + 8*(reg>>2) + 4*hi (m)
    float bv[2];
#pragma unroll
    for (int j = 0; j < 2; ++j)
        bv[j] = HESS ? 0.f : bias[bn + wn + j * 32 + lm];
#pragma unroll
    for (int i = 0; i < 2; ++i) {
        const size_t mbase = bm + wm + i * 32 + 4 * hi;
#pragma unroll
        for (int j = 0; j < 2; ++j) {
            const size_t n = bn + wn + j * 32 + lm;
#pragma unroll
            for (int reg = 0; reg < 16; ++reg) {
                const size_t m = mbase + (reg & 3) + 8 * (reg >> 2);
                float v = acc[i][j][reg] + bv[j];
                if (HESS && m == n) v += 1e-4f;
                C[m * N + n] = v;
            }
        }
    }
}

extern "C" void kernel_launch(void* const* d_in, const int* in_sizes, int n_in,
                              void* d_out, int out_size, void* d_ws, size_t ws_size,
                              hipStream_t stream) {
    const float* x = (const float*)d_in[0];   // [8192, 4096]
    const float* W = (const float*)d_in[1];   // [4096, 4096]
    const float* b = (const float*)d_in[2];   // [4096]

    float* out  = (float*)d_out;                       // [8192, 4096]
    float* hess = out + (size_t)BDIM * DOUTD;          // [4096, 4096]

    // workspace layout (bf16): xb [B,D] | xT [D,B] | Wb [DOUT,D]  = 168 MB
    unsigned short* xb = (unsigned short*)d_ws;
    unsigned short* xT = xb + (size_t)BDIM * DDIM;
    unsigned short* Wb = xT + (size_t)BDIM * DDIM;

    convert_transpose_x<<<dim3(BDIM / 64, DDIM / 64), 256, 0, stream>>>(x, xb, xT);
    convert_w_kernel<<<((size_t)DOUTD * DDIM) / 1024, 256, 0, stream>>>(W, Wb);

    // out = x @ W.T + b : M=8192, N=4096, K=4096
    gemm_nt<false><<<dim3(BDIM / 128, DOUTD / 128), 256, 0, stream>>>(
        xb, Wb, b, out, BDIM, DOUTD, DDIM);
    // hess = xT @ xT.T + eps*I : M=N=4096, K=8192
    gemm_nt<true><<<dim3(DDIM / 128, DDIM / 128), 256, 0, stream>>>(
        xT, xT, nullptr, hess, DDIM, DDIM, BDIM);
}